// Round 2
// baseline (318.786 us; speedup 1.0000x reference)
//
#include <hip/hip_runtime.h>
#include <hip/hip_bf16.h>

#define T_TOK 2048
#define H_DIM 1024
#define E_EXP 32
#define F_DIM 512
#define FS_DIM 1024
#define K_TOP 8
#define NGRP 8
#define TGRP 4
#define GSZ (E_EXP / NGRP)
#define RSCALE 2.5f
#define CAP 2048

typedef short  short8 __attribute__((ext_vector_type(8)));
typedef __bf16 bf16x4 __attribute__((ext_vector_type(4)));
typedef float  f32x4  __attribute__((ext_vector_type(4)));

// ---------------- fp32 -> bf16 conversion ----------------
__global__ void cvt_f32_bf16(const float* __restrict__ src, __bf16* __restrict__ dst, int n4) {
  int i = blockIdx.x * blockDim.x + threadIdx.x;
  const int stride = gridDim.x * blockDim.x;
  for (; i < n4; i += stride) {
    const float4 v = reinterpret_cast<const float4*>(src)[i];
    bf16x4 o;
    o[0] = (__bf16)v.x; o[1] = (__bf16)v.y; o[2] = (__bf16)v.z; o[3] = (__bf16)v.w;
    reinterpret_cast<bf16x4*>(dst)[i] = o;
  }
}

// ---------------- routing (fp32, exact reference semantics) ----------------
__global__ __launch_bounds__(64) void route_kernel(
    const float* __restrict__ x, const float* __restrict__ gw,
    const float* __restrict__ bias, int* __restrict__ tk_idx, float* __restrict__ tk_w) {
  const int t = blockIdx.x;
  const int lane = threadIdx.x;
  float xr[16];
#pragma unroll
  for (int i = 0; i < 16; i++) xr[i] = x[t * H_DIM + i * 64 + lane];
  float sc[E_EXP];
#pragma unroll
  for (int e = 0; e < E_EXP; e++) {
    const float* w = gw + e * H_DIM;
    float s = 0.f;
#pragma unroll
    for (int i = 0; i < 16; i++) s += xr[i] * w[i * 64 + lane];
#pragma unroll
    for (int off = 32; off > 0; off >>= 1) s += __shfl_xor(s, off);
    sc[e] = 1.f / (1.f + expf(-s));
  }
  if (lane == 0) {
    float b[E_EXP];
    for (int e = 0; e < E_EXP; e++) b[e] = sc[e] + bias[e];
    // group score = sum of top-2 biased scores within each group of 4
    float gs[NGRP];
    for (int g = 0; g < NGRP; g++) {
      float m1 = -1e30f, m2 = -1e30f;
      for (int j = 0; j < GSZ; j++) {
        float v = b[g * GSZ + j];
        if (v > m1) { m2 = m1; m1 = v; } else if (v > m2) { m2 = v; }
      }
      gs[g] = m1 + m2;
    }
    // top-4 groups (strict > : ties -> lower index, matches lax.top_k)
    unsigned gmask = 0;
    for (int it = 0; it < TGRP; it++) {
      float best = -1e30f; int bi = 0;
      for (int g = 0; g < NGRP; g++)
        if (!((gmask >> g) & 1) && gs[g] > best) { best = gs[g]; bi = g; }
      gmask |= 1u << bi;
    }
    // top-8 experts among selected groups
    unsigned emask = 0; float wsum = 0.f;
    int idx8[K_TOP];
    for (int it = 0; it < K_TOP; it++) {
      float best = -1e30f; int bi = 0;
      for (int e = 0; e < E_EXP; e++) {
        if (!((gmask >> (e / GSZ)) & 1)) continue;
        if ((emask >> e) & 1) continue;
        if (b[e] > best) { best = b[e]; bi = e; }
      }
      emask |= 1u << bi;
      idx8[it] = bi;
      wsum += sc[bi];
    }
    const float inv = 1.f / (wsum + 1e-20f);
    for (int k = 0; k < K_TOP; k++) {
      tk_idx[t * K_TOP + k] = idx8[k];
      tk_w[t * K_TOP + k] = sc[idx8[k]] * inv;
    }
  }
}

// ---------------- scatter: build per-expert token lists ----------------
__global__ void scatter_kernel(const int* __restrict__ tk_idx, int* __restrict__ counts,
                               int* __restrict__ recs) {
  const int i = blockIdx.x * blockDim.x + threadIdx.x;
  if (i >= T_TOK * K_TOP) return;
  const int e = tk_idx[i];
  const int pos = atomicAdd(&counts[e], 1);
  recs[e * CAP + pos] = i;  // i == t*8 + k
}

__global__ void offsets_kernel(const int* __restrict__ counts, int* __restrict__ offs) {
  if (threadIdx.x == 0) {
    int a = 0;
    for (int e = 0; e < E_EXP; e++) { offs[e] = a; a += counts[e]; }
  }
}

// ---------------- grouped GEMM (m97 structure, 4x1 wave split) ----------------
#define BM 128
#define BN 128
#define BK 64

constexpr int MODE_GU = 0, MODE_DOWN = 1, MODE_SGU = 2, MODE_SDOWN = 3;

__device__ __forceinline__ void gload_lds16(const void* g, void* l) {
  __builtin_amdgcn_global_load_lds(
      (__attribute__((address_space(1))) const void*)g,
      (__attribute__((address_space(3))) void*)l, 16, 0, 0);
}

template <int MODE>
__global__ __launch_bounds__(256) void gemm_kernel(
    const __bf16* __restrict__ Abase, const __bf16* __restrict__ Bbase,
    void* __restrict__ Out,
    const int* __restrict__ recs, const int* __restrict__ counts,
    const int* __restrict__ offs, const float* __restrict__ tk_w) {

  constexpr int K = (MODE == MODE_DOWN) ? F_DIM : ((MODE == MODE_SDOWN) ? FS_DIM : H_DIM);

  const int e = (MODE == MODE_GU || MODE == MODE_DOWN) ? blockIdx.z : 0;
  const int m0 = blockIdx.y * BM;
  int count = T_TOK, off_e = 0;
  if (MODE == MODE_GU || MODE == MODE_DOWN) {
    count = counts[e];
    off_e = offs[e];
    if (m0 >= count) return;
  }
  const int tid = threadIdx.x, wid = tid >> 6, lane = tid & 63;

  __shared__ __align__(16) __bf16 As[BM * BK];
  __shared__ __align__(16) __bf16 Bs[BN * BK];

  const int colk = (lane & 7) * 8;  // k-offset (elements) handled by this lane
  const __bf16* aptr[4];
  const __bf16* bptr[4];
#pragma unroll
  for (int i = 0; i < 4; i++) {
    const int row = wid * 32 + i * 8 + (lane >> 3);
    // ---- A source ----
    if (MODE == MODE_GU) {
      int r = m0 + row; if (r > count - 1) r = count - 1;
      const int rec = recs[e * CAP + r];
      aptr[i] = Abase + (size_t)(rec >> 3) * H_DIM + colk;       // gather token row of xb
    } else if (MODE == MODE_DOWN) {
      int r = m0 + row; if (r > count - 1) r = count - 1;
      aptr[i] = Abase + (size_t)(off_e + r) * F_DIM + colk;      // dense h slab
    } else {
      aptr[i] = Abase + (size_t)(m0 + row) * K + colk;           // dense
    }
    // ---- B source ----
    int brow;
    if (MODE == MODE_GU)       brow = (row < 64) ? (blockIdx.x * 64 + row) : (F_DIM + blockIdx.x * 64 + row - 64);
    else if (MODE == MODE_SGU) brow = (row < 64) ? (blockIdx.x * 64 + row) : (FS_DIM + blockIdx.x * 64 + row - 64);
    else                       brow = blockIdx.x * BN + row;
    const __bf16* bexp = Bbase +
        ((MODE == MODE_GU)   ? (size_t)e * 2 * F_DIM * H_DIM :
         (MODE == MODE_DOWN) ? (size_t)e * H_DIM * F_DIM : (size_t)0);
    bptr[i] = bexp + (size_t)brow * K + colk;
  }

  f32x4 acc[2][8];
#pragma unroll
  for (int a = 0; a < 2; a++)
#pragma unroll
    for (int b = 0; b < 8; b++) acc[a][b] = f32x4{0.f, 0.f, 0.f, 0.f};

  const int lr = lane & 15, lh = lane >> 4;

  for (int k0 = 0; k0 < K; k0 += BK) {
#pragma unroll
    for (int i = 0; i < 4; i++)
      gload_lds16(aptr[i] + k0, (char*)As + (wid * 4 + i) * 1024);
#pragma unroll
    for (int i = 0; i < 4; i++)
      gload_lds16(bptr[i] + k0, (char*)Bs + (wid * 4 + i) * 1024);
    __syncthreads();
#pragma unroll
    for (int kk = 0; kk < 2; kk++) {
      short8 af[2], bfr[8];
#pragma unroll
      for (int fm = 0; fm < 2; fm++)
        af[fm] = *reinterpret_cast<const short8*>(&As[(wid * 32 + fm * 16 + lr) * BK + kk * 32 + lh * 8]);
#pragma unroll
      for (int fn = 0; fn < 8; fn++)
        bfr[fn] = *reinterpret_cast<const short8*>(&Bs[(fn * 16 + lr) * BK + kk * 32 + lh * 8]);
#pragma unroll
      for (int fn = 0; fn < 8; fn++)
#pragma unroll
        for (int fm = 0; fm < 2; fm++)
          acc[fm][fn] = __builtin_amdgcn_mfma_f32_16x16x32_bf16(af[fm], bfr[fn], acc[fm][fn], 0, 0, 0);
    }
    __syncthreads();
  }

  // ---------------- epilogues ----------------
  if (MODE == MODE_GU) {
    __bf16* h_out = (__bf16*)Out;
#pragma unroll
    for (int fm = 0; fm < 2; fm++)
#pragma unroll
      for (int j = 0; j < 4; j++) {
        const int row = wid * 32 + fm * 16 + lh * 4 + j;
        if (m0 + row < count) {
#pragma unroll
          for (int fn = 0; fn < 4; fn++) {
            const float g = acc[fm][fn][j], u = acc[fm][fn + 4][j];
            const float hv = g / (1.f + expf(-g)) * u;
            const int f = blockIdx.x * 64 + fn * 16 + lr;
            h_out[(size_t)(off_e + m0 + row) * F_DIM + f] = (__bf16)hv;
          }
        }
      }
  } else if (MODE == MODE_SGU) {
    __bf16* h_out = (__bf16*)Out;
#pragma unroll
    for (int fm = 0; fm < 2; fm++)
#pragma unroll
      for (int j = 0; j < 4; j++) {
        const int row = wid * 32 + fm * 16 + lh * 4 + j;
#pragma unroll
        for (int fn = 0; fn < 4; fn++) {
          const float g = acc[fm][fn][j], u = acc[fm][fn + 4][j];
          const float hv = g / (1.f + expf(-g)) * u;
          const int f = blockIdx.x * 64 + fn * 16 + lr;
          h_out[(size_t)(m0 + row) * FS_DIM + f] = (__bf16)hv;
        }
      }
  } else if (MODE == MODE_DOWN) {
    float* y = (float*)Out;
#pragma unroll
    for (int fm = 0; fm < 2; fm++)
#pragma unroll
      for (int j = 0; j < 4; j++) {
        const int row = wid * 32 + fm * 16 + lh * 4 + j;
        if (m0 + row < count) {
          const int rec = recs[e * CAP + m0 + row];   // == t*8+k, the y_slot row
          const float w = tk_w[rec];
          const size_t base = (size_t)rec * H_DIM + blockIdx.x * BN;
#pragma unroll
          for (int fn = 0; fn < 8; fn++)
            y[base + fn * 16 + lr] = acc[fm][fn][j] * w;
        }
      }
  } else {  // MODE_SDOWN: write shared-expert output (fp32) straight to d_out
    float* o = (float*)Out;
#pragma unroll
    for (int fm = 0; fm < 2; fm++)
#pragma unroll
      for (int j = 0; j < 4; j++) {
        const int row = wid * 32 + fm * 16 + lh * 4 + j;
#pragma unroll
        for (int fn = 0; fn < 8; fn++)
          o[(size_t)(m0 + row) * H_DIM + blockIdx.x * BN + fn * 16 + lr] = acc[fm][fn][j];
      }
  }
}

// ---------------- combine: out = shared + SCALE * sum_k y_slot[t,k] ----------------
__global__ void combine_kernel(const float* __restrict__ y_slot, float* __restrict__ out) {
  const int gid = blockIdx.x * blockDim.x + threadIdx.x;  // one per 4 elements
  const int t = gid >> 8;
  const int c0 = (gid & 255) * 4;
  float4 s = {0.f, 0.f, 0.f, 0.f};
#pragma unroll
  for (int k = 0; k < K_TOP; k++) {
    const float4 v = *reinterpret_cast<const float4*>(&y_slot[((size_t)t * K_TOP + k) * H_DIM + c0]);
    s.x += v.x; s.y += v.y; s.z += v.z; s.w += v.w;
  }
  float4 o = *reinterpret_cast<float4*>(&out[(size_t)t * H_DIM + c0]);
  o.x += RSCALE * s.x; o.y += RSCALE * s.y; o.z += RSCALE * s.z; o.w += RSCALE * s.w;
  *reinterpret_cast<float4*>(&out[(size_t)t * H_DIM + c0]) = o;
}

// ---------------- launch ----------------
extern "C" void kernel_launch(void* const* d_in, const int* in_sizes, int n_in,
                              void* d_out, int out_size, void* d_ws, size_t ws_size,
                              hipStream_t stream) {
  const float* x    = (const float*)d_in[0];
  const float* gw   = (const float*)d_in[1];
  const float* bias = (const float*)d_in[2];
  const float* wgu  = (const float*)d_in[3];
  const float* wd   = (const float*)d_in[4];
  const float* sgu  = (const float*)d_in[5];
  const float* sd   = (const float*)d_in[6];

  char* ws = (char*)d_ws;
  size_t o = 0;
  auto alloc = [&](size_t bytes) {
    char* p = ws + o;
    o += (bytes + 255) & ~(size_t)255;
    return (void*)p;
  };
  __bf16* xb     = (__bf16*)alloc((size_t)T_TOK * H_DIM * 2);
  __bf16* wgub   = (__bf16*)alloc((size_t)E_EXP * 2 * F_DIM * H_DIM * 2);
  __bf16* wdb    = (__bf16*)alloc((size_t)E_EXP * H_DIM * F_DIM * 2);
  __bf16* sgub   = (__bf16*)alloc((size_t)2 * FS_DIM * H_DIM * 2);
  __bf16* sdb    = (__bf16*)alloc((size_t)H_DIM * FS_DIM * 2);
  __bf16* h_buf  = (__bf16*)alloc((size_t)T_TOK * K_TOP * F_DIM * 2);
  float*  y_slot = (float*) alloc((size_t)T_TOK * K_TOP * H_DIM * 4);
  __bf16* hs     = (__bf16*)alloc((size_t)T_TOK * FS_DIM * 2);
  int*   tk_idx  = (int*)  alloc((size_t)T_TOK * K_TOP * 4);
  float* tk_w    = (float*)alloc((size_t)T_TOK * K_TOP * 4);
  int*   counts  = (int*)  alloc((size_t)E_EXP * 4);
  int*   offs    = (int*)  alloc((size_t)E_EXP * 4);
  int*   recs    = (int*)  alloc((size_t)E_EXP * CAP * 4);
  if (o > ws_size) return;  // workspace too small: bail (will show as validation failure)

  // 1. conversions
  cvt_f32_bf16<<<2048, 256, 0, stream>>>(x,   xb,   T_TOK * H_DIM / 4);
  cvt_f32_bf16<<<2048, 256, 0, stream>>>(wgu, wgub, E_EXP * 2 * F_DIM * H_DIM / 4);
  cvt_f32_bf16<<<2048, 256, 0, stream>>>(wd,  wdb,  E_EXP * H_DIM * F_DIM / 4);
  cvt_f32_bf16<<<2048, 256, 0, stream>>>(sgu, sgub, 2 * FS_DIM * H_DIM / 4);
  cvt_f32_bf16<<<1024, 256, 0, stream>>>(sd,  sdb,  H_DIM * FS_DIM / 4);

  // 2. routing
  route_kernel<<<T_TOK, 64, 0, stream>>>(x, gw, bias, tk_idx, tk_w);

  // 3. scatter
  hipMemsetAsync(counts, 0, E_EXP * 4, stream);
  scatter_kernel<<<(T_TOK * K_TOP + 255) / 256, 256, 0, stream>>>(tk_idx, counts, recs);
  offsets_kernel<<<1, 64, 0, stream>>>(counts, offs);

  // 4. grouped GEMMs
  gemm_kernel<MODE_GU>   <<<dim3(F_DIM / 64, T_TOK / BM, E_EXP), 256, 0, stream>>>(xb, wgub, h_buf, recs, counts, offs, tk_w);
  gemm_kernel<MODE_DOWN> <<<dim3(H_DIM / BN, T_TOK / BM, E_EXP), 256, 0, stream>>>(h_buf, wdb, y_slot, recs, counts, offs, tk_w);
  gemm_kernel<MODE_SGU>  <<<dim3(FS_DIM / 64, T_TOK / BM, 1), 256, 0, stream>>>(xb, sgub, hs, recs, counts, offs, tk_w);
  gemm_kernel<MODE_SDOWN><<<dim3(H_DIM / BN, T_TOK / BM, 1), 256, 0, stream>>>(hs, sdb, d_out, recs, counts, offs, tk_w);

  // 5. combine
  combine_kernel<<<T_TOK * H_DIM / 4 / 256, 256, 0, stream>>>(y_slot, (float*)d_out);
}